// Round 2
// baseline (974.913 us; speedup 1.0000x reference)
//
#include <hip/hip_runtime.h>

#define NN 8192
#define CAP 128          // max nnz per Laplacian row (mean ~34, P(>70) ~ 1e-8)

typedef __attribute__((ext_vector_type(8))) short bf16x8;
typedef __attribute__((ext_vector_type(4))) float f32x4;

__device__ __forceinline__ short f2bf(float f) {
    unsigned u = __builtin_bit_cast(unsigned, f);
    u += 0x7FFFu + ((u >> 16) & 1u);          // round-to-nearest-even
    return (short)(u >> 16);
}

// ---------------------------------------------------------------- z = x @ W
__global__ __launch_bounds__(256) void k_small_gemm(
        const float* __restrict__ x, const float* __restrict__ Wdown,
        const float* __restrict__ Wup, const float* __restrict__ Whar,
        float* __restrict__ zbuf) {
    int wsel = blockIdx.y;
    const float* W = (wsel == 0) ? Wdown : (wsel == 1) ? Wdown + 16384 :
                     (wsel == 2) ? Wup   : (wsel == 3) ? Wup + 16384 : Whar;
    float* out = zbuf + (size_t)wsel * NN * 128;
    __shared__ float Wl[128 * 128];
    __shared__ float Xl[32 * 128];
    int tid = threadIdx.x;
    int row0 = blockIdx.x * 32;
    const float4* W4 = (const float4*)W;
    float4* Wl4 = (float4*)Wl;
    for (int i = tid; i < 4096; i += 256) Wl4[i] = W4[i];
    const float4* X4 = (const float4*)(x + (size_t)row0 * 128);
    float4* Xl4 = (float4*)Xl;
    for (int i = tid; i < 1024; i += 256) Xl4[i] = X4[i];
    __syncthreads();
    int tx = tid & 31, ty = tid >> 5;
    float acc[4][4] = {};
#pragma unroll 2
    for (int i = 0; i < 128; ++i) {
        float w0 = Wl[i * 128 + tx];
        float w1 = Wl[i * 128 + tx + 32];
        float w2 = Wl[i * 128 + tx + 64];
        float w3 = Wl[i * 128 + tx + 96];
#pragma unroll
        for (int rr = 0; rr < 4; ++rr) {
            float xv = Xl[(ty * 4 + rr) * 128 + i];
            acc[rr][0] += xv * w0; acc[rr][1] += xv * w1;
            acc[rr][2] += xv * w2; acc[rr][3] += xv * w3;
        }
    }
#pragma unroll
    for (int rr = 0; rr < 4; ++rr) {
        float* o = out + (size_t)(row0 + ty * 4 + rr) * 128 + tx;
        o[0] = acc[rr][0]; o[32] = acc[rr][1]; o[64] = acc[rr][2]; o[96] = acc[rr][3];
    }
}

// ------------------------------------------------- s,t = z_r @ a_src / a_tgt
__global__ __launch_bounds__(256) void k_st(
        const float* __restrict__ zbuf, const float* __restrict__ a_down,
        const float* __restrict__ a_up, float* __restrict__ stbuf) {
    int sel = blockIdx.y;
    const float* z0 = zbuf + (size_t)sel * 2 * NN * 128;
    const float* z1 = z0 + (size_t)NN * 128;
    const float* a = sel ? a_up : a_down;
    int row = ((int)blockIdx.x * 256 + (int)threadIdx.x) >> 6;
    int lane = threadIdx.x & 63;
    float z0a = z0[(size_t)row * 128 + lane], z0b = z0[(size_t)row * 128 + lane + 64];
    float z1a = z1[(size_t)row * 128 + lane], z1b = z1[(size_t)row * 128 + lane + 64];
    float ps = z0a * a[lane]       + z0b * a[lane + 64]
             + z1a * a[128 + lane] + z1b * a[192 + lane];
    float pt = z0a * a[256 + lane] + z0b * a[320 + lane]
             + z1a * a[384 + lane] + z1b * a[448 + lane];
    for (int off = 32; off; off >>= 1) {
        ps += __shfl_xor(ps, off);
        pt += __shfl_xor(pt, off);
    }
    if (lane == 0) {
        stbuf[(size_t)sel * 2 * NN + row] = ps;
        stbuf[(size_t)sel * 2 * NN + NN + row] = pt;
    }
}

// -------------------------------------- one-pass nonzero scan -> padded CSR
__global__ __launch_bounds__(256) void k_scan(
        const float* __restrict__ lapdown, const float* __restrict__ lapup,
        int* __restrict__ cntbuf, int* __restrict__ colbuf) {
    int sel = blockIdx.y;
    const float* lap = sel ? lapup : lapdown;
    int row = ((int)blockIdx.x * 256 + (int)threadIdx.x) >> 6;
    int lane = threadIdx.x & 63;
    const float4* lr = (const float4*)(lap + (size_t)row * NN);
    int* crow = colbuf + (size_t)sel * NN * CAP + (size_t)row * CAP;
    unsigned long long ltmask = (1ull << lane) - 1ull;
    int c = 0;
    for (int it = 0; it < 32; ++it) {
        float4 v = lr[it * 64 + lane];
#pragma unroll
        for (int q = 0; q < 4; ++q) {
            float f = (q == 0) ? v.x : (q == 1) ? v.y : (q == 2) ? v.z : v.w;
            bool nz = (f != 0.0f);
            unsigned long long m = __ballot(nz);
            if (nz) {
                int slot = c + __popcll(m & ltmask);
                if (slot < CAP) crow[slot] = it * 256 + lane * 4 + q;
            }
            c += __popcll(m);
        }
    }
    if (lane == 0) cntbuf[sel * NN + row] = (c < CAP) ? c : CAP;
}

// ----------------------------- per-edge softmax weights (masked elu-softmax)
__global__ __launch_bounds__(256) void k_att(
        const float* __restrict__ stbuf, const int* __restrict__ cntbuf,
        const int* __restrict__ colbuf, float* __restrict__ valbuf) {
    int sel = blockIdx.y;
    const float* s = stbuf + (size_t)sel * 2 * NN;
    const float* t = s + NN;
    int row = ((int)blockIdx.x * 256 + (int)threadIdx.x) >> 6;
    int lane = threadIdx.x & 63;
    int c = cntbuf[sel * NN + row];
    const int* cr = colbuf + (size_t)sel * NN * CAP + (size_t)row * CAP;
    float* vr = valbuf + (size_t)sel * NN * CAP + (size_t)row * CAP;
    float tv = t[row];
    float e0 = -1e30f, e1 = -1e30f;
    if (lane < c)      { float v = tv + s[cr[lane]];      e0 = v > 0.f ? v : expm1f(v); }
    if (lane + 64 < c) { float v = tv + s[cr[lane + 64]]; e1 = v > 0.f ? v : expm1f(v); }
    float m = fmaxf(e0, e1);
    for (int off = 32; off; off >>= 1) m = fmaxf(m, __shfl_xor(m, off));
    float p0 = (lane < c)      ? expf(e0 - m) : 0.f;
    float p1 = (lane + 64 < c) ? expf(e1 - m) : 0.f;
    float sum = p0 + p1;
    for (int off = 32; off; off >>= 1) sum += __shfl_xor(sum, off);
    float inv = 1.0f / sum;
    if (lane < c)      vr[lane] = p0 * inv;
    if (lane + 64 < c) vr[lane + 64] = p1 * inv;
}

// ---------------------------------- h (8192x128 f32) -> hT (128x8192 bf16)
__global__ __launch_bounds__(512) void k_tr(
        const float* __restrict__ h, unsigned short* __restrict__ hT) {
    __shared__ unsigned short tile[32 * 128];
    int tid = threadIdx.x;
    int k0 = blockIdx.x * 32;
    int r = tid >> 4;
    int c0 = (tid & 15) * 8;
    const float4* src = (const float4*)(h + (size_t)(k0 + r) * 128 + c0);
    float4 a = src[0], b = src[1];
    unsigned short* tp = &tile[r * 128 + c0];
    tp[0] = (unsigned short)f2bf(a.x); tp[1] = (unsigned short)f2bf(a.y);
    tp[2] = (unsigned short)f2bf(a.z); tp[3] = (unsigned short)f2bf(a.w);
    tp[4] = (unsigned short)f2bf(b.x); tp[5] = (unsigned short)f2bf(b.y);
    tp[6] = (unsigned short)f2bf(b.z); tp[7] = (unsigned short)f2bf(b.w);
    __syncthreads();
    int c = tid & 127;
    int seg = tid >> 7;
    unsigned short v[8];
#pragma unroll
    for (int i = 0; i < 8; ++i) v[i] = tile[(seg * 8 + i) * 128 + c];
    uint4 pack;
    pack.x = (unsigned)v[0] | ((unsigned)v[1] << 16);
    pack.y = (unsigned)v[2] | ((unsigned)v[3] << 16);
    pack.z = (unsigned)v[4] | ((unsigned)v[5] << 16);
    pack.w = (unsigned)v[6] | ((unsigned)v[7] << 16);
    *(uint4*)(hT + (size_t)c * NN + k0 + seg * 8) = pack;
}

// --------------------- z_har = proj @ h  (bf16 MFMA, on-the-fly A convert)
__global__ __launch_bounds__(256) void k_proj(
        const float* __restrict__ P, const unsigned short* __restrict__ hT,
        float* __restrict__ partial) {
    int gw = ((int)blockIdx.x * 256 + (int)threadIdx.x) >> 6;
    int lane = threadIdx.x & 63;
    int strip = gw >> 3;
    int ks = gw & 7;
    int row0 = strip * 16;
    int k0 = ks * 1024;
    int l15 = lane & 15;
    int koff = (lane >> 4) * 8;
    const float* A = P + (size_t)(row0 + l15) * NN + k0 + koff;
    const unsigned short* B0 = hT + (size_t)l15 * NN + k0 + koff;
    f32x4 acc[8];
#pragma unroll
    for (int i = 0; i < 8; ++i) acc[i] = (f32x4){0.f, 0.f, 0.f, 0.f};
#pragma unroll 2
    for (int kc = 0; kc < 32; ++kc) {
        int k = kc * 32;
        float4 a0 = *(const float4*)(A + k);
        float4 a1 = *(const float4*)(A + k + 4);
        bf16x8 af;
        af[0] = f2bf(a0.x); af[1] = f2bf(a0.y); af[2] = f2bf(a0.z); af[3] = f2bf(a0.w);
        af[4] = f2bf(a1.x); af[5] = f2bf(a1.y); af[6] = f2bf(a1.z); af[7] = f2bf(a1.w);
#pragma unroll
        for (int ct = 0; ct < 8; ++ct) {
            bf16x8 bf = *(const bf16x8*)(B0 + (size_t)ct * 16 * NN + k);
            acc[ct] = __builtin_amdgcn_mfma_f32_16x16x32_bf16(af, bf, acc[ct], 0, 0, 0);
        }
    }
    float* out = partial + (size_t)ks * NN * 128;
    int prow = row0 + (lane >> 4) * 4;
#pragma unroll
    for (int ct = 0; ct < 8; ++ct)
#pragma unroll
        for (int r = 0; r < 4; ++r)
            out[(size_t)(prow + r) * 128 + ct * 16 + l15] = acc[ct][r];
}

// ------------------------------------------- d_out = sum of 8 K-split parts
__global__ __launch_bounds__(256) void k_reduce(
        const float4* __restrict__ partial, float4* __restrict__ out) {
    int i = blockIdx.x * 256 + threadIdx.x;
    float4 s = partial[i];
#pragma unroll
    for (int ks = 1; ks < 8; ++ks) {
        float4 p = partial[(size_t)ks * 262144 + i];
        s.x += p.x; s.y += p.y; s.z += p.z; s.w += p.w;
    }
    out[i] = s;
}

// ------------------- y[row] (+)= sum_e val_e * (B1[col_e] (+ B2[col_e]))
__global__ __launch_bounds__(256) void k_spmm(
        const int* __restrict__ cnt, const int* __restrict__ col,
        const float* __restrict__ val, const float* __restrict__ B1,
        const float* __restrict__ B2, float* __restrict__ out, int accumulate) {
    int row = ((int)blockIdx.x * 256 + (int)threadIdx.x) >> 6;
    int lane = threadIdx.x & 63;
    int c = cnt[row];
    const int* cr = col + (size_t)row * CAP;
    const float* vr = val + (size_t)row * CAP;
    float ax = 0.f, ay = 0.f;
    for (int e = 0; e < c; ++e) {
        int j = cr[e];
        float v = vr[e];
        float2 b = ((const float2*)(B1 + (size_t)j * 128))[lane];
        if (B2) {
            float2 b2 = ((const float2*)(B2 + (size_t)j * 128))[lane];
            b.x += b2.x; b.y += b2.y;
        }
        ax += v * b.x; ay += v * b.y;
    }
    float2* o = (float2*)(out + (size_t)row * 128);
    float2 rres;
    if (accumulate) { float2 p = o[lane]; rres.x = p.x + ax; rres.y = p.y + ay; }
    else            { rres.x = ax; rres.y = ay; }
    o[lane] = rres;
}

extern "C" void kernel_launch(void* const* d_in, const int* in_sizes, int n_in,
                              void* d_out, int out_size, void* d_ws, size_t ws_size,
                              hipStream_t stream) {
    const float* x        = (const float*)d_in[0];
    const float* lap_up   = (const float*)d_in[1];
    const float* lap_down = (const float*)d_in[2];
    const float* proj     = (const float*)d_in[3];
    const float* W_up     = (const float*)d_in[4];
    const float* a_up     = (const float*)d_in[5];
    const float* W_down   = (const float*)d_in[6];
    const float* a_down   = (const float*)d_in[7];
    const float* W_har    = (const float*)d_in[8];
    float* out = (float*)d_out;
    float* ws = (float*)d_ws;

    const size_t ZSZ = (size_t)NN * 128;
    size_t off = 0;
    float* zbuf = ws + off;              off += 5 * ZSZ;
    float* stbuf = ws + off;             off += 4 * NN;
    int* cntbuf = (int*)(ws + off);      off += 2 * NN;
    int* colbuf = (int*)(ws + off);      off += 2 * (size_t)NN * CAP;
    float* valbuf = ws + off;            off += 2 * (size_t)NN * CAP;
    float* y1 = ws + off;                off += ZSZ;
    unsigned short* hT = (unsigned short*)(ws + off); off += ZSZ / 2;
    float* partial = ws + off;           off += 8 * ZSZ;

    hipLaunchKernelGGL(k_small_gemm, dim3(256, 5), dim3(256), 0, stream,
                       x, W_down, W_up, W_har, zbuf);
    hipLaunchKernelGGL(k_st, dim3(2048, 2), dim3(256), 0, stream,
                       zbuf, a_down, a_up, stbuf);
    hipLaunchKernelGGL(k_scan, dim3(2048, 2), dim3(256), 0, stream,
                       lap_down, lap_up, cntbuf, colbuf);
    hipLaunchKernelGGL(k_att, dim3(2048, 2), dim3(256), 0, stream,
                       stbuf, cntbuf, colbuf, valbuf);
    hipLaunchKernelGGL(k_tr, dim3(256), dim3(512), 0, stream,
                       zbuf + 4 * ZSZ, hT);
    hipLaunchKernelGGL(k_proj, dim3(1024), dim3(256), 0, stream,
                       proj, hT, partial);
    hipLaunchKernelGGL(k_reduce, dim3(1024), dim3(256), 0, stream,
                       (const float4*)partial, (float4*)out);
    hipLaunchKernelGGL(k_spmm, dim3(2048), dim3(256), 0, stream,
                       cntbuf, colbuf, valbuf, zbuf + ZSZ, (const float*)nullptr, y1, 0);
    hipLaunchKernelGGL(k_spmm, dim3(2048), dim3(256), 0, stream,
                       cntbuf, colbuf, valbuf, zbuf, y1, out, 1);
    hipLaunchKernelGGL(k_spmm, dim3(2048), dim3(256), 0, stream,
                       cntbuf + NN, colbuf + (size_t)NN * CAP, valbuf + (size_t)NN * CAP,
                       zbuf + 3 * ZSZ, (const float*)nullptr, y1, 0);
    hipLaunchKernelGGL(k_spmm, dim3(2048), dim3(256), 0, stream,
                       cntbuf + NN, colbuf + (size_t)NN * CAP, valbuf + (size_t)NN * CAP,
                       zbuf + 2 * ZSZ, y1, out, 1);
}

// Round 3
// 936.503 us; speedup vs baseline: 1.0410x; 1.0410x over previous
//
#include <hip/hip_runtime.h>

#define NN 8192
#define CAP 128          // max nnz per Laplacian row (mean ~34, P(>70) ~ 1e-8)

typedef __attribute__((ext_vector_type(8))) short bf16x8;
typedef __attribute__((ext_vector_type(4))) float f32x4;

__device__ __forceinline__ short f2bf(float f) {
    unsigned u = __builtin_bit_cast(unsigned, f);
    u += 0x7FFFu + ((u >> 16) & 1u);          // round-to-nearest-even
    return (short)(u >> 16);
}

// ---------------------------------------------------------------- z = x @ W
__global__ __launch_bounds__(256) void k_small_gemm(
        const float* __restrict__ x, const float* __restrict__ Wdown,
        const float* __restrict__ Wup, const float* __restrict__ Whar,
        float* __restrict__ zbuf) {
    int wsel = blockIdx.y;
    const float* W = (wsel == 0) ? Wdown : (wsel == 1) ? Wdown + 16384 :
                     (wsel == 2) ? Wup   : (wsel == 3) ? Wup + 16384 : Whar;
    float* out = zbuf + (size_t)wsel * NN * 128;
    __shared__ float Wl[128 * 128];
    __shared__ float Xl[32 * 128];
    int tid = threadIdx.x;
    int row0 = blockIdx.x * 32;
    const float4* W4 = (const float4*)W;
    float4* Wl4 = (float4*)Wl;
    for (int i = tid; i < 4096; i += 256) Wl4[i] = W4[i];
    const float4* X4 = (const float4*)(x + (size_t)row0 * 128);
    float4* Xl4 = (float4*)Xl;
    for (int i = tid; i < 1024; i += 256) Xl4[i] = X4[i];
    __syncthreads();
    int tx = tid & 31, ty = tid >> 5;
    float acc[4][4] = {};
#pragma unroll 2
    for (int i = 0; i < 128; ++i) {
        float w0 = Wl[i * 128 + tx];
        float w1 = Wl[i * 128 + tx + 32];
        float w2 = Wl[i * 128 + tx + 64];
        float w3 = Wl[i * 128 + tx + 96];
#pragma unroll
        for (int rr = 0; rr < 4; ++rr) {
            float xv = Xl[(ty * 4 + rr) * 128 + i];
            acc[rr][0] += xv * w0; acc[rr][1] += xv * w1;
            acc[rr][2] += xv * w2; acc[rr][3] += xv * w3;
        }
    }
#pragma unroll
    for (int rr = 0; rr < 4; ++rr) {
        float* o = out + (size_t)(row0 + ty * 4 + rr) * 128 + tx;
        o[0] = acc[rr][0]; o[32] = acc[rr][1]; o[64] = acc[rr][2]; o[96] = acc[rr][3];
    }
}

// ------------------------------------------------- s,t = z_r @ a_src / a_tgt
__global__ __launch_bounds__(256) void k_st(
        const float* __restrict__ zbuf, const float* __restrict__ a_down,
        const float* __restrict__ a_up, float* __restrict__ stbuf) {
    int sel = blockIdx.y;
    const float* z0 = zbuf + (size_t)sel * 2 * NN * 128;
    const float* z1 = z0 + (size_t)NN * 128;
    const float* a = sel ? a_up : a_down;
    int row = ((int)blockIdx.x * 256 + (int)threadIdx.x) >> 6;
    int lane = threadIdx.x & 63;
    float z0a = z0[(size_t)row * 128 + lane], z0b = z0[(size_t)row * 128 + lane + 64];
    float z1a = z1[(size_t)row * 128 + lane], z1b = z1[(size_t)row * 128 + lane + 64];
    float ps = z0a * a[lane]       + z0b * a[lane + 64]
             + z1a * a[128 + lane] + z1b * a[192 + lane];
    float pt = z0a * a[256 + lane] + z0b * a[320 + lane]
             + z1a * a[384 + lane] + z1b * a[448 + lane];
    for (int off = 32; off; off >>= 1) {
        ps += __shfl_xor(ps, off);
        pt += __shfl_xor(pt, off);
    }
    if (lane == 0) {
        stbuf[(size_t)sel * 2 * NN + row] = ps;
        stbuf[(size_t)sel * 2 * NN + NN + row] = pt;
    }
}

// ------------------- one-pass nonzero scan -> padded CSR (pad cols = 0)
__global__ __launch_bounds__(256) void k_scan(
        const float* __restrict__ lapdown, const float* __restrict__ lapup,
        int* __restrict__ cntbuf, int* __restrict__ colbuf) {
    int sel = blockIdx.y;
    const float* lap = sel ? lapup : lapdown;
    int row = ((int)blockIdx.x * 256 + (int)threadIdx.x) >> 6;
    int lane = threadIdx.x & 63;
    const float4* lr = (const float4*)(lap + (size_t)row * NN);
    int* crow = colbuf + (size_t)sel * NN * CAP + (size_t)row * CAP;
    unsigned long long ltmask = (1ull << lane) - 1ull;
    int c = 0;
    for (int it = 0; it < 32; ++it) {
        float4 v = lr[it * 64 + lane];
#pragma unroll
        for (int q = 0; q < 4; ++q) {
            float f = (q == 0) ? v.x : (q == 1) ? v.y : (q == 2) ? v.z : v.w;
            bool nz = (f != 0.0f);
            unsigned long long m = __ballot(nz);
            if (nz) {
                int slot = c + __popcll(m & ltmask);
                if (slot < CAP) crow[slot] = it * 256 + lane * 4 + q;
            }
            c += __popcll(m);
        }
    }
    int cc = (c < CAP) ? c : CAP;
    int cpad = (cc + 7) & ~7;
    if (lane < cpad - cc) crow[cc + lane] = 0;      // pad col -> row 0 (val 0)
    if (lane == 0) cntbuf[sel * NN + row] = cc;
}

// --------- per-edge softmax weights (masked elu-softmax), pad vals = 0
__global__ __launch_bounds__(256) void k_att(
        const float* __restrict__ stbuf, const int* __restrict__ cntbuf,
        const int* __restrict__ colbuf, float* __restrict__ valbuf) {
    int sel = blockIdx.y;
    const float* s = stbuf + (size_t)sel * 2 * NN;
    const float* t = s + NN;
    int row = ((int)blockIdx.x * 256 + (int)threadIdx.x) >> 6;
    int lane = threadIdx.x & 63;
    int c = cntbuf[sel * NN + row];
    const int* cr = colbuf + (size_t)sel * NN * CAP + (size_t)row * CAP;
    float* vr = valbuf + (size_t)sel * NN * CAP + (size_t)row * CAP;
    float tv = t[row];
    float e0 = -1e30f, e1 = -1e30f;
    if (lane < c)      { float v = tv + s[cr[lane]];      e0 = v > 0.f ? v : expm1f(v); }
    if (lane + 64 < c) { float v = tv + s[cr[lane + 64]]; e1 = v > 0.f ? v : expm1f(v); }
    float m = fmaxf(e0, e1);
    for (int off = 32; off; off >>= 1) m = fmaxf(m, __shfl_xor(m, off));
    float p0 = (lane < c)      ? expf(e0 - m) : 0.f;
    float p1 = (lane + 64 < c) ? expf(e1 - m) : 0.f;
    float sum = p0 + p1;
    for (int off = 32; off; off >>= 1) sum += __shfl_xor(sum, off);
    float inv = 1.0f / sum;
    if (lane < c)      vr[lane] = p0 * inv;
    if (lane + 64 < c) vr[lane + 64] = p1 * inv;
    int cpad = (c + 7) & ~7;
    if (lane < cpad - c) vr[c + lane] = 0.f;        // zero the pad slots
}

// ---------------------------------- h (8192x128 f32) -> hT (128x8192 bf16)
__global__ __launch_bounds__(512) void k_tr(
        const float* __restrict__ h, unsigned short* __restrict__ hT) {
    __shared__ unsigned short tile[32 * 128];
    int tid = threadIdx.x;
    int k0 = blockIdx.x * 32;
    int r = tid >> 4;
    int c0 = (tid & 15) * 8;
    const float4* src = (const float4*)(h + (size_t)(k0 + r) * 128 + c0);
    float4 a = src[0], b = src[1];
    unsigned short* tp = &tile[r * 128 + c0];
    tp[0] = (unsigned short)f2bf(a.x); tp[1] = (unsigned short)f2bf(a.y);
    tp[2] = (unsigned short)f2bf(a.z); tp[3] = (unsigned short)f2bf(a.w);
    tp[4] = (unsigned short)f2bf(b.x); tp[5] = (unsigned short)f2bf(b.y);
    tp[6] = (unsigned short)f2bf(b.z); tp[7] = (unsigned short)f2bf(b.w);
    __syncthreads();
    int c = tid & 127;
    int seg = tid >> 7;
    unsigned short v[8];
#pragma unroll
    for (int i = 0; i < 8; ++i) v[i] = tile[(seg * 8 + i) * 128 + c];
    uint4 pack;
    pack.x = (unsigned)v[0] | ((unsigned)v[1] << 16);
    pack.y = (unsigned)v[2] | ((unsigned)v[3] << 16);
    pack.z = (unsigned)v[4] | ((unsigned)v[5] << 16);
    pack.w = (unsigned)v[6] | ((unsigned)v[7] << 16);
    *(uint4*)(hT + (size_t)c * NN + k0 + seg * 8) = pack;
}

// ---- z_har partials = proj @ h (bf16 MFMA, on-the-fly A convert, A-prefetch)
__global__ __launch_bounds__(256) void k_proj(
        const float* __restrict__ P, const unsigned short* __restrict__ hT,
        float* __restrict__ partial, int lgnks) {
    int gw = ((int)blockIdx.x * 256 + (int)threadIdx.x) >> 6;
    int lane = threadIdx.x & 63;
    int nksm1 = (1 << lgnks) - 1;
    int strip = gw >> lgnks;
    int ks = gw & nksm1;
    int kiters = 256 >> lgnks;
    int row0 = strip * 16;
    int k0 = ks << (13 - lgnks);
    int l15 = lane & 15;
    int koff = (lane >> 4) * 8;
    const float* A = P + (size_t)(row0 + l15) * NN + k0 + koff;
    const unsigned short* B0 = hT + (size_t)l15 * NN + k0 + koff;
    f32x4 acc[8];
#pragma unroll
    for (int i = 0; i < 8; ++i) acc[i] = (f32x4){0.f, 0.f, 0.f, 0.f};
    float4 a0 = *(const float4*)(A);
    float4 a1 = *(const float4*)(A + 4);
    for (int kc = 0; kc < kiters; ++kc) {
        float4 n0, n1;
        if (kc + 1 < kiters) {                       // prefetch next A chunk
            const float* An = A + 32 * (kc + 1);
            n0 = *(const float4*)(An);
            n1 = *(const float4*)(An + 4);
        }
        bf16x8 af;
        af[0] = f2bf(a0.x); af[1] = f2bf(a0.y); af[2] = f2bf(a0.z); af[3] = f2bf(a0.w);
        af[4] = f2bf(a1.x); af[5] = f2bf(a1.y); af[6] = f2bf(a1.z); af[7] = f2bf(a1.w);
        const unsigned short* Bp = B0 + kc * 32;
#pragma unroll
        for (int ct = 0; ct < 8; ++ct) {
            bf16x8 bf = *(const bf16x8*)(Bp + (size_t)ct * 16 * NN);
            acc[ct] = __builtin_amdgcn_mfma_f32_16x16x32_bf16(af, bf, acc[ct], 0, 0, 0);
        }
        a0 = n0; a1 = n1;
    }
    float* out = partial + (size_t)ks * NN * 128;
    int prow = row0 + (lane >> 4) * 4;
#pragma unroll
    for (int ct = 0; ct < 8; ++ct)
#pragma unroll
        for (int r = 0; r < 4; ++r)
            out[(size_t)(prow + r) * 128 + ct * 16 + l15] = acc[ct][r];
}

// ---------------- unrolled padded-CSR gather: acc += sum_e val_e * B[col_e]
__device__ __forceinline__ void edge_acc(
        int c, const int* __restrict__ cr, const float* __restrict__ vr,
        const float* __restrict__ B, int lane, float& ax, float& ay) {
    int cpad = (c + 7) & ~7;
    for (int e = 0; e < cpad; e += 8) {
        int4   j0 = *(const int4*)(cr + e);
        int4   j1 = *(const int4*)(cr + e + 4);
        float4 v0 = *(const float4*)(vr + e);
        float4 v1 = *(const float4*)(vr + e + 4);
        float2 b0 = ((const float2*)(B + (size_t)j0.x * 128))[lane];
        float2 b1 = ((const float2*)(B + (size_t)j0.y * 128))[lane];
        float2 b2 = ((const float2*)(B + (size_t)j0.z * 128))[lane];
        float2 b3 = ((const float2*)(B + (size_t)j0.w * 128))[lane];
        float2 b4 = ((const float2*)(B + (size_t)j1.x * 128))[lane];
        float2 b5 = ((const float2*)(B + (size_t)j1.y * 128))[lane];
        float2 b6 = ((const float2*)(B + (size_t)j1.z * 128))[lane];
        float2 b7 = ((const float2*)(B + (size_t)j1.w * 128))[lane];
        ax += v0.x * b0.x; ay += v0.x * b0.y;
        ax += v0.y * b1.x; ay += v0.y * b1.y;
        ax += v0.z * b2.x; ay += v0.z * b2.y;
        ax += v0.w * b3.x; ay += v0.w * b3.y;
        ax += v1.x * b4.x; ay += v1.x * b4.y;
        ax += v1.y * b5.x; ay += v1.y * b5.y;
        ax += v1.z * b6.x; ay += v1.z * b6.y;
        ax += v1.w * b7.x; ay += v1.w * b7.y;
    }
}

// -------------------------- pass 1: w_sel = z_sel0 + A_sel @ z_sel1
__global__ __launch_bounds__(256) void k_pass1(
        const int* __restrict__ cnt, const int* __restrict__ col,
        const float* __restrict__ val, const float* __restrict__ zbuf,
        float* __restrict__ wbuf) {
    int sel = blockIdx.y;
    const float* z0 = zbuf + (size_t)sel * 2 * NN * 128;
    const float* z1 = z0 + (size_t)NN * 128;
    float* w = wbuf + (size_t)sel * NN * 128;
    int row = ((int)blockIdx.x * 256 + (int)threadIdx.x) >> 6;
    int lane = threadIdx.x & 63;
    int c = cnt[sel * NN + row];
    float2 a = ((const float2*)(z0 + (size_t)row * 128))[lane];
    float ax = a.x, ay = a.y;
    edge_acc(c, col + ((size_t)sel * NN + row) * CAP,
             val + ((size_t)sel * NN + row) * CAP, z1, lane, ax, ay);
    ((float2*)(w + (size_t)row * 128))[lane] = make_float2(ax, ay);
}

// ---------- final: out = sum_ks partial + A_d @ w_d + A_u @ w_u
__global__ __launch_bounds__(256) void k_final(
        const int* __restrict__ cnt, const int* __restrict__ col,
        const float* __restrict__ val, const float* __restrict__ wbuf,
        const float* __restrict__ partial, int nks, float* __restrict__ out) {
    int row = ((int)blockIdx.x * 256 + (int)threadIdx.x) >> 6;
    int lane = threadIdx.x & 63;
    float ax = 0.f, ay = 0.f;
    for (int ks = 0; ks < nks; ++ks) {
        float2 p = ((const float2*)(partial + (size_t)ks * NN * 128 + (size_t)row * 128))[lane];
        ax += p.x; ay += p.y;
    }
    // down conv
    edge_acc(cnt[row], col + (size_t)row * CAP, val + (size_t)row * CAP,
             wbuf, lane, ax, ay);
    // up conv
    edge_acc(cnt[NN + row], col + ((size_t)NN + row) * CAP,
             val + ((size_t)NN + row) * CAP, wbuf + (size_t)NN * 128, lane, ax, ay);
    ((float2*)(out + (size_t)row * 128))[lane] = make_float2(ax, ay);
}

extern "C" void kernel_launch(void* const* d_in, const int* in_sizes, int n_in,
                              void* d_out, int out_size, void* d_ws, size_t ws_size,
                              hipStream_t stream) {
    const float* x        = (const float*)d_in[0];
    const float* lap_up   = (const float*)d_in[1];
    const float* lap_down = (const float*)d_in[2];
    const float* proj     = (const float*)d_in[3];
    const float* W_up     = (const float*)d_in[4];
    const float* a_up     = (const float*)d_in[5];
    const float* W_down   = (const float*)d_in[6];
    const float* a_down   = (const float*)d_in[7];
    const float* W_har    = (const float*)d_in[8];
    float* out = (float*)d_out;
    float* ws = (float*)d_ws;

    const size_t ZSZ = (size_t)NN * 128;      // 1,048,576 floats
    // fixed part of the workspace (in float slots)
    const size_t fixed = 5 * ZSZ + 4 * NN + 2 * NN + 2 * ZSZ + 2 * ZSZ
                       + 2 * ZSZ + ZSZ / 2;
    int lgnks = 4;                             // prefer 16 K-splits
    while (lgnks > 2 && (fixed + ((size_t)1 << lgnks) * ZSZ) * 4 > ws_size) --lgnks;
    int nks = 1 << lgnks;

    size_t off = 0;
    float* zbuf = ws + off;              off += 5 * ZSZ;   // z_d0,z_d1,z_u0,z_u1,h
    float* stbuf = ws + off;             off += 4 * NN;    // s_d,t_d,s_u,t_u
    int* cntbuf = (int*)(ws + off);      off += 2 * NN;
    int* colbuf = (int*)(ws + off);      off += 2 * ZSZ;
    float* valbuf = ws + off;            off += 2 * ZSZ;
    float* wbuf = ws + off;              off += 2 * ZSZ;   // w_d, w_u
    unsigned short* hT = (unsigned short*)(ws + off); off += ZSZ / 2;
    float* partial = ws + off;           off += (size_t)nks * ZSZ;

    hipLaunchKernelGGL(k_small_gemm, dim3(256, 5), dim3(256), 0, stream,
                       x, W_down, W_up, W_har, zbuf);
    hipLaunchKernelGGL(k_st, dim3(2048, 2), dim3(256), 0, stream,
                       zbuf, a_down, a_up, stbuf);
    hipLaunchKernelGGL(k_scan, dim3(2048, 2), dim3(256), 0, stream,
                       lap_down, lap_up, cntbuf, colbuf);
    hipLaunchKernelGGL(k_att, dim3(2048, 2), dim3(256), 0, stream,
                       stbuf, cntbuf, colbuf, valbuf);
    hipLaunchKernelGGL(k_tr, dim3(256), dim3(512), 0, stream,
                       zbuf + 4 * ZSZ, hT);
    hipLaunchKernelGGL(k_proj, dim3(128 * nks), dim3(256), 0, stream,
                       proj, hT, partial, lgnks);
    hipLaunchKernelGGL(k_pass1, dim3(2048, 2), dim3(256), 0, stream,
                       cntbuf, colbuf, valbuf, zbuf, wbuf);
    hipLaunchKernelGGL(k_final, dim3(2048), dim3(256), 0, stream,
                       cntbuf, colbuf, valbuf, wbuf, partial, nks, out);
}

// Round 4
// 820.942 us; speedup vs baseline: 1.1876x; 1.1408x over previous
//
#include <hip/hip_runtime.h>

#define NN 8192
#define CAP 128          // max nnz per Laplacian row (mean ~34)
#define PLDA 68          // A LDS row stride (64+4 floats)
#define PLDB 72          // B LDS row stride (64+8 shorts)

typedef __attribute__((ext_vector_type(8))) short bf16x8;
typedef __attribute__((ext_vector_type(4))) float f32x4;

__device__ __forceinline__ short f2bf(float f) {
    unsigned u = __builtin_bit_cast(unsigned, f);
    u += 0x7FFFu + ((u >> 16) & 1u);          // round-to-nearest-even
    return (short)(u >> 16);
}

// ---------------------------------------------------------------- z = x @ W
__global__ __launch_bounds__(256) void k_small_gemm(
        const float* __restrict__ x, const float* __restrict__ Wdown,
        const float* __restrict__ Wup, const float* __restrict__ Whar,
        float* __restrict__ zbuf) {
    int wsel = blockIdx.y;
    const float* W = (wsel == 0) ? Wdown : (wsel == 1) ? Wdown + 16384 :
                     (wsel == 2) ? Wup   : (wsel == 3) ? Wup + 16384 : Whar;
    float* out = zbuf + (size_t)wsel * NN * 128;
    __shared__ float Wl[128 * 128];
    __shared__ float Xl[32 * 128];
    int tid = threadIdx.x;
    int row0 = blockIdx.x * 32;
    const float4* W4 = (const float4*)W;
    float4* Wl4 = (float4*)Wl;
    for (int i = tid; i < 4096; i += 256) Wl4[i] = W4[i];
    const float4* X4 = (const float4*)(x + (size_t)row0 * 128);
    float4* Xl4 = (float4*)Xl;
    for (int i = tid; i < 1024; i += 256) Xl4[i] = X4[i];
    __syncthreads();
    int tx = tid & 31, ty = tid >> 5;
    float acc[4][4] = {};
#pragma unroll 2
    for (int i = 0; i < 128; ++i) {
        float w0 = Wl[i * 128 + tx];
        float w1 = Wl[i * 128 + tx + 32];
        float w2 = Wl[i * 128 + tx + 64];
        float w3 = Wl[i * 128 + tx + 96];
#pragma unroll
        for (int rr = 0; rr < 4; ++rr) {
            float xv = Xl[(ty * 4 + rr) * 128 + i];
            acc[rr][0] += xv * w0; acc[rr][1] += xv * w1;
            acc[rr][2] += xv * w2; acc[rr][3] += xv * w3;
        }
    }
#pragma unroll
    for (int rr = 0; rr < 4; ++rr) {
        float* o = out + (size_t)(row0 + ty * 4 + rr) * 128 + tx;
        o[0] = acc[rr][0]; o[32] = acc[rr][1]; o[64] = acc[rr][2]; o[96] = acc[rr][3];
    }
}

// ------------------------------------------------- s,t = z_r @ a_src / a_tgt
__global__ __launch_bounds__(256) void k_st(
        const float* __restrict__ zbuf, const float* __restrict__ a_down,
        const float* __restrict__ a_up, float* __restrict__ stbuf) {
    int sel = blockIdx.y;
    const float* z0 = zbuf + (size_t)sel * 2 * NN * 128;
    const float* z1 = z0 + (size_t)NN * 128;
    const float* a = sel ? a_up : a_down;
    int row = ((int)blockIdx.x * 256 + (int)threadIdx.x) >> 6;
    int lane = threadIdx.x & 63;
    float z0a = z0[(size_t)row * 128 + lane], z0b = z0[(size_t)row * 128 + lane + 64];
    float z1a = z1[(size_t)row * 128 + lane], z1b = z1[(size_t)row * 128 + lane + 64];
    float ps = z0a * a[lane]       + z0b * a[lane + 64]
             + z1a * a[128 + lane] + z1b * a[192 + lane];
    float pt = z0a * a[256 + lane] + z0b * a[320 + lane]
             + z1a * a[384 + lane] + z1b * a[448 + lane];
    for (int off = 32; off; off >>= 1) {
        ps += __shfl_xor(ps, off);
        pt += __shfl_xor(pt, off);
    }
    if (lane == 0) {
        stbuf[(size_t)sel * 2 * NN + row] = ps;
        stbuf[(size_t)sel * 2 * NN + NN + row] = pt;
    }
}

// ---- fused: nonzero scan -> padded CSR + masked elu-softmax edge weights
__global__ __launch_bounds__(256) void k_scanatt(
        const float* __restrict__ lapdown, const float* __restrict__ lapup,
        const float* __restrict__ stbuf,
        int* __restrict__ cntbuf, int* __restrict__ colbuf,
        float* __restrict__ valbuf) {
    __shared__ int colsh[4][CAP];            // per-wave col stash (avoids RAW)
    int sel = blockIdx.y;
    const float* lap = sel ? lapup : lapdown;
    int wid = threadIdx.x >> 6;
    int row = (int)blockIdx.x * 4 + wid;
    int lane = threadIdx.x & 63;
    const float4* lr = (const float4*)(lap + (size_t)row * NN);
    int* crow = colbuf + (size_t)sel * NN * CAP + (size_t)row * CAP;
    int* csh = colsh[wid];
    unsigned long long ltmask = (1ull << lane) - 1ull;
    int c = 0;
    for (int it = 0; it < 32; ++it) {
        float4 v = lr[it * 64 + lane];
#pragma unroll
        for (int q = 0; q < 4; ++q) {
            float f = (q == 0) ? v.x : (q == 1) ? v.y : (q == 2) ? v.z : v.w;
            bool nz = (f != 0.0f);
            unsigned long long m = __ballot(nz);
            if (nz) {
                int slot = c + __popcll(m & ltmask);
                if (slot < CAP) {
                    int cidx = it * 256 + lane * 4 + q;
                    crow[slot] = cidx;
                    csh[slot] = cidx;
                }
            }
            c += __popcll(m);
        }
    }
    int cc = (c < CAP) ? c : CAP;
    int cpad = (cc + 7) & ~7;
    if (lane < cpad - cc) crow[cc + lane] = 0;      // pad col -> row 0 (val 0)
    if (lane == 0) cntbuf[sel * NN + row] = cc;
    // --------- softmax over the cc edges of this row
    const float* s = stbuf + (size_t)sel * 2 * NN;
    const float* t = s + NN;
    float* vr = valbuf + (size_t)sel * NN * CAP + (size_t)row * CAP;
    float tv = t[row];
    float e0 = -1e30f, e1 = -1e30f;
    if (lane < cc)      { float v = tv + s[csh[lane]];      e0 = v > 0.f ? v : expm1f(v); }
    if (lane + 64 < cc) { float v = tv + s[csh[lane + 64]]; e1 = v > 0.f ? v : expm1f(v); }
    float m = fmaxf(e0, e1);
    for (int off = 32; off; off >>= 1) m = fmaxf(m, __shfl_xor(m, off));
    float p0 = (lane < cc)      ? expf(e0 - m) : 0.f;
    float p1 = (lane + 64 < cc) ? expf(e1 - m) : 0.f;
    float sum = p0 + p1;
    for (int off = 32; off; off >>= 1) sum += __shfl_xor(sum, off);
    float inv = 1.0f / sum;
    if (lane < cc)      vr[lane] = p0 * inv;
    if (lane + 64 < cc) vr[lane + 64] = p1 * inv;
    if (lane < cpad - cc) vr[cc + lane] = 0.f;      // zero the pad slots
}

// ---------------------------------- h (8192x128 f32) -> hT (128x8192 bf16)
__global__ __launch_bounds__(512) void k_tr(
        const float* __restrict__ h, unsigned short* __restrict__ hT) {
    __shared__ unsigned short tile[32 * 128];
    int tid = threadIdx.x;
    int k0 = blockIdx.x * 32;
    int r = tid >> 4;
    int c0 = (tid & 15) * 8;
    const float4* src = (const float4*)(h + (size_t)(k0 + r) * 128 + c0);
    float4 a = src[0], b = src[1];
    unsigned short* tp = &tile[r * 128 + c0];
    tp[0] = (unsigned short)f2bf(a.x); tp[1] = (unsigned short)f2bf(a.y);
    tp[2] = (unsigned short)f2bf(a.z); tp[3] = (unsigned short)f2bf(a.w);
    tp[4] = (unsigned short)f2bf(b.x); tp[5] = (unsigned short)f2bf(b.y);
    tp[6] = (unsigned short)f2bf(b.z); tp[7] = (unsigned short)f2bf(b.w);
    __syncthreads();
    int c = tid & 127;
    int seg = tid >> 7;
    unsigned short v[8];
#pragma unroll
    for (int i = 0; i < 8; ++i) v[i] = tile[(seg * 8 + i) * 128 + c];
    uint4 pack;
    pack.x = (unsigned)v[0] | ((unsigned)v[1] << 16);
    pack.y = (unsigned)v[2] | ((unsigned)v[3] << 16);
    pack.z = (unsigned)v[4] | ((unsigned)v[5] << 16);
    pack.w = (unsigned)v[6] | ((unsigned)v[7] << 16);
    *(uint4*)(hT + (size_t)c * NN + k0 + seg * 8) = pack;
}

// ---- z_har partials = proj @ h : LDS double-buffered, reg-staged pipeline
// BM=64, BN=128 (full N), BK=64; 4 waves; grid = 128 strips x 4 K-splits
__global__ __launch_bounds__(256) void k_proj(
        const float* __restrict__ P, const unsigned short* __restrict__ hT,
        float* __restrict__ partial) {
    __shared__ float As[2][64 * PLDA];               // 34816 B
    __shared__ unsigned short Bs[2][128 * PLDB];     // 36864 B
    int tid = threadIdx.x;
    int strip = (int)blockIdx.x >> 2;
    int ks = (int)blockIdx.x & 3;
    int RB = strip * 64;
    int k0 = ks * 2048;
    int w = tid >> 6, lane = tid & 63;
    int l15 = lane & 15, koff = (lane >> 4) * 8;
    // staging map: A: thread -> (row=tid/4, 16 f32 at (tid%4)*16)
    //              B: thread -> (n=tid/2, 32 shorts at (tid%2)*32)
    int ar = tid >> 2, ak = (tid & 3) * 16;
    int bn = tid >> 1, bk = (tid & 1) * 32;
    const float* Ag = P + (size_t)(RB + ar) * NN + k0 + ak;
    const unsigned short* Bg = hT + (size_t)bn * NN + k0 + bk;
    float* Aw0 = &As[0][ar * PLDA + ak];
    unsigned short* Bw0 = &Bs[0][bn * PLDB + bk];
    float* Aw1 = &As[1][ar * PLDA + ak];
    unsigned short* Bw1 = &Bs[1][bn * PLDB + bk];

    float4 sa[4]; uint4 sb[4];
#pragma unroll
    for (int i = 0; i < 4; ++i) sa[i] = *(const float4*)(Ag + i * 4);
#pragma unroll
    for (int i = 0; i < 4; ++i) sb[i] = *(const uint4*)(Bg + i * 8);
#pragma unroll
    for (int i = 0; i < 4; ++i) *(float4*)(Aw0 + i * 4) = sa[i];
#pragma unroll
    for (int i = 0; i < 4; ++i) *(uint4*)(Bw0 + i * 8) = sb[i];
    __syncthreads();

    f32x4 acc[8];
#pragma unroll
    for (int i = 0; i < 8; ++i) acc[i] = (f32x4){0.f, 0.f, 0.f, 0.f};

    for (int t = 0; t < 32; ++t) {
        int cur = t & 1;
        if (t + 1 < 32) {                            // issue next tile loads
            const float* Agn = Ag + (t + 1) * 64;
            const unsigned short* Bgn = Bg + (t + 1) * 64;
#pragma unroll
            for (int i = 0; i < 4; ++i) sa[i] = *(const float4*)(Agn + i * 4);
#pragma unroll
            for (int i = 0; i < 4; ++i) sb[i] = *(const uint4*)(Bgn + i * 8);
        }
        // compute current tile
#pragma unroll
        for (int kk = 0; kk < 2; ++kk) {
            const float* Ab = &As[cur][(w * 16 + l15) * PLDA + kk * 32 + koff];
            float4 a0 = *(const float4*)Ab;
            float4 a1 = *(const float4*)(Ab + 4);
            bf16x8 af;
            af[0] = f2bf(a0.x); af[1] = f2bf(a0.y); af[2] = f2bf(a0.z); af[3] = f2bf(a0.w);
            af[4] = f2bf(a1.x); af[5] = f2bf(a1.y); af[6] = f2bf(a1.z); af[7] = f2bf(a1.w);
#pragma unroll
            for (int ct = 0; ct < 8; ++ct) {
                bf16x8 bf = *(const bf16x8*)(&Bs[cur][(ct * 16 + l15) * PLDB + kk * 32 + koff]);
                acc[ct] = __builtin_amdgcn_mfma_f32_16x16x32_bf16(af, bf, acc[ct], 0, 0, 0);
            }
        }
        if (t + 1 < 32) {                            // write into other buffer
            float* Aw = (cur ? Aw0 : Aw1);
            unsigned short* Bw = (cur ? Bw0 : Bw1);
#pragma unroll
            for (int i = 0; i < 4; ++i) *(float4*)(Aw + i * 4) = sa[i];
#pragma unroll
            for (int i = 0; i < 4; ++i) *(uint4*)(Bw + i * 8) = sb[i];
        }
        __syncthreads();
    }
    float* out = partial + (size_t)ks * NN * 128;
    int prow = RB + w * 16 + (lane >> 4) * 4;
#pragma unroll
    for (int ct = 0; ct < 8; ++ct)
#pragma unroll
        for (int r = 0; r < 4; ++r)
            out[(size_t)(prow + r) * 128 + ct * 16 + l15] = acc[ct][r];
}

// ---------------- unrolled padded-CSR gather: acc += sum_e val_e * B[col_e]
__device__ __forceinline__ void edge_acc(
        int c, const int* __restrict__ cr, const float* __restrict__ vr,
        const float* __restrict__ B, int lane, float& ax, float& ay) {
    int cpad = (c + 7) & ~7;
    for (int e = 0; e < cpad; e += 8) {
        int4   j0 = *(const int4*)(cr + e);
        int4   j1 = *(const int4*)(cr + e + 4);
        float4 v0 = *(const float4*)(vr + e);
        float4 v1 = *(const float4*)(vr + e + 4);
        float2 b0 = ((const float2*)(B + (size_t)j0.x * 128))[lane];
        float2 b1 = ((const float2*)(B + (size_t)j0.y * 128))[lane];
        float2 b2 = ((const float2*)(B + (size_t)j0.z * 128))[lane];
        float2 b3 = ((const float2*)(B + (size_t)j0.w * 128))[lane];
        float2 b4 = ((const float2*)(B + (size_t)j1.x * 128))[lane];
        float2 b5 = ((const float2*)(B + (size_t)j1.y * 128))[lane];
        float2 b6 = ((const float2*)(B + (size_t)j1.z * 128))[lane];
        float2 b7 = ((const float2*)(B + (size_t)j1.w * 128))[lane];
        ax += v0.x * b0.x; ay += v0.x * b0.y;
        ax += v0.y * b1.x; ay += v0.y * b1.y;
        ax += v0.z * b2.x; ay += v0.z * b2.y;
        ax += v0.w * b3.x; ay += v0.w * b3.y;
        ax += v1.x * b4.x; ay += v1.x * b4.y;
        ax += v1.y * b5.x; ay += v1.y * b5.y;
        ax += v1.z * b6.x; ay += v1.z * b6.y;
        ax += v1.w * b7.x; ay += v1.w * b7.y;
    }
}

// -------------------------- pass 1: w_sel = z_sel0 + A_sel @ z_sel1
__global__ __launch_bounds__(256) void k_pass1(
        const int* __restrict__ cnt, const int* __restrict__ col,
        const float* __restrict__ val, const float* __restrict__ zbuf,
        float* __restrict__ wbuf) {
    int sel = blockIdx.y;
    const float* z0 = zbuf + (size_t)sel * 2 * NN * 128;
    const float* z1 = z0 + (size_t)NN * 128;
    float* w = wbuf + (size_t)sel * NN * 128;
    int row = ((int)blockIdx.x * 256 + (int)threadIdx.x) >> 6;
    int lane = threadIdx.x & 63;
    int c = cnt[sel * NN + row];
    float2 a = ((const float2*)(z0 + (size_t)row * 128))[lane];
    float ax = a.x, ay = a.y;
    edge_acc(c, col + ((size_t)sel * NN + row) * CAP,
             val + ((size_t)sel * NN + row) * CAP, z1, lane, ax, ay);
    ((float2*)(w + (size_t)row * 128))[lane] = make_float2(ax, ay);
}

// ---------- final: out = sum_ks partial + A_d @ w_d + A_u @ w_u
__global__ __launch_bounds__(256) void k_final(
        const int* __restrict__ cnt, const int* __restrict__ col,
        const float* __restrict__ val, const float* __restrict__ wbuf,
        const float* __restrict__ partial, float* __restrict__ out) {
    int row = ((int)blockIdx.x * 256 + (int)threadIdx.x) >> 6;
    int lane = threadIdx.x & 63;
    float ax = 0.f, ay = 0.f;
#pragma unroll
    for (int ks = 0; ks < 4; ++ks) {
        float2 p = ((const float2*)(partial + (size_t)ks * NN * 128 + (size_t)row * 128))[lane];
        ax += p.x; ay += p.y;
    }
    edge_acc(cnt[row], col + (size_t)row * CAP, val + (size_t)row * CAP,
             wbuf, lane, ax, ay);
    edge_acc(cnt[NN + row], col + ((size_t)NN + row) * CAP,
             val + ((size_t)NN + row) * CAP, wbuf + (size_t)NN * 128, lane, ax, ay);
    ((float2*)(out + (size_t)row * 128))[lane] = make_float2(ax, ay);
}

extern "C" void kernel_launch(void* const* d_in, const int* in_sizes, int n_in,
                              void* d_out, int out_size, void* d_ws, size_t ws_size,
                              hipStream_t stream) {
    const float* x        = (const float*)d_in[0];
    const float* lap_up   = (const float*)d_in[1];
    const float* lap_down = (const float*)d_in[2];
    const float* proj     = (const float*)d_in[3];
    const float* W_up     = (const float*)d_in[4];
    const float* a_up     = (const float*)d_in[5];
    const float* W_down   = (const float*)d_in[6];
    const float* a_down   = (const float*)d_in[7];
    const float* W_har    = (const float*)d_in[8];
    float* out = (float*)d_out;
    float* ws = (float*)d_ws;

    const size_t ZSZ = (size_t)NN * 128;      // 1,048,576 floats
    size_t off = 0;
    float* zbuf = ws + off;              off += 5 * ZSZ;   // z_d0,z_d1,z_u0,z_u1,h
    float* stbuf = ws + off;             off += 4 * NN;    // s_d,t_d,s_u,t_u
    int* cntbuf = (int*)(ws + off);      off += 2 * NN;
    int* colbuf = (int*)(ws + off);      off += 2 * ZSZ;
    float* valbuf = ws + off;            off += 2 * ZSZ;
    float* wbuf = ws + off;              off += 2 * ZSZ;   // w_d, w_u
    unsigned short* hT = (unsigned short*)(ws + off); off += ZSZ / 2;
    float* partial = ws + off;           off += 4 * ZSZ;   // ~64 MB total

    hipLaunchKernelGGL(k_small_gemm, dim3(256, 5), dim3(256), 0, stream,
                       x, W_down, W_up, W_har, zbuf);
    hipLaunchKernelGGL(k_st, dim3(2048, 2), dim3(256), 0, stream,
                       zbuf, a_down, a_up, stbuf);
    hipLaunchKernelGGL(k_scanatt, dim3(2048, 2), dim3(256), 0, stream,
                       lap_down, lap_up, stbuf, cntbuf, colbuf, valbuf);
    hipLaunchKernelGGL(k_tr, dim3(256), dim3(512), 0, stream,
                       zbuf + 4 * ZSZ, hT);
    hipLaunchKernelGGL(k_proj, dim3(512), dim3(256), 0, stream,
                       proj, hT, partial);
    hipLaunchKernelGGL(k_pass1, dim3(2048, 2), dim3(256), 0, stream,
                       cntbuf, colbuf, valbuf, zbuf, wbuf);
    hipLaunchKernelGGL(k_final, dim3(2048), dim3(256), 0, stream,
                       cntbuf, colbuf, valbuf, wbuf, partial, out);
}